// Round 6
// baseline (397.231 us; speedup 1.0000x reference)
//
#include <hip/hip_runtime.h>
#include <hip/hip_fp16.h>

#define ALIGNUP(x) (((x) + 255) & ~(size_t)255)
#define ABLK 256          // blocks for hist/scatter passes
#define BSHIFT 9          // 512 dst nodes per bucket; requires N <= 131072

// ---------------- CSR build: two-level counting sort, LDS atomics only ----------------

__global__ void bucket_hist_kernel(const int* __restrict__ col, unsigned* __restrict__ gHist,
                                   int nE, int chunk) {
    __shared__ unsigned hist[256];
    const int tid = threadIdx.x, blk = blockIdx.x;
    hist[tid] = 0;
    __syncthreads();
    const int e0 = blk * chunk, e1 = min(nE, e0 + chunk);
    for (int e = e0 + tid; e < e1; e += 256)
        atomicAdd(&hist[((unsigned)col[e]) >> BSHIFT], 1u);
    __syncthreads();
    gHist[tid * ABLK + blk] = hist[tid];   // bucket-major
}

// exclusive scan over all 256*ABLK entries, single block of 1024 threads, 64 elems/thread
__global__ void bucket_scan_kernel(unsigned* __restrict__ g) {
    __shared__ unsigned ps[1024];
    const int tid = threadIdx.x;
    const int base = tid * 64;
    unsigned sum = 0;
    for (int k = 0; k < 64; ++k) sum += g[base + k];
    ps[tid] = sum;
    __syncthreads();
    for (int o = 1; o < 1024; o <<= 1) {
        unsigned t = tid >= o ? ps[tid - o] : 0u;
        __syncthreads();
        ps[tid] += t;
        __syncthreads();
    }
    unsigned run = ps[tid] - sum;   // exclusive base for this thread's span
    for (int k = 0; k < 64; ++k) {
        unsigned v = g[base + k];
        g[base + k] = run;
        run += v;
    }
}

__global__ void bucket_scatter_kernel(const int* __restrict__ row, const int* __restrict__ col,
                                      const unsigned* __restrict__ gScan,
                                      unsigned* __restrict__ pairs, int nE, int chunk) {
    __shared__ unsigned basec[256];
    const int tid = threadIdx.x, blk = blockIdx.x;
    basec[tid] = gScan[tid * ABLK + blk];
    __syncthreads();
    const int e0 = blk * chunk, e1 = min(nE, e0 + chunk);
    for (int e = e0 + tid; e < e1; e += 256) {
        unsigned d = (unsigned)col[e];
        unsigned pos = atomicAdd(&basec[d >> BSHIFT], 1u);
        pairs[pos] = (((unsigned)row[e]) << BSHIFT) | (d & 511u);  // src(17b) | dstLow(9b)
    }
}

// one block per bucket: count per-node, scan, emit dinv/off and dst-sorted srcs
__global__ void bucket_sort_kernel(const unsigned* __restrict__ pairs,
                                   const unsigned* __restrict__ gScan,
                                   int* __restrict__ srcs, int* __restrict__ off,
                                   float* __restrict__ dinv, int nN, int nE) {
    __shared__ unsigned cnt[512], sc[512];
    const int tid = threadIdx.x, b = blockIdx.x;
    const unsigned s = gScan[b * ABLK];
    const unsigned t = (b + 1 < 256) ? gScan[(b + 1) * ABLK] : (unsigned)nE;
    cnt[tid] = 0;
    __syncthreads();
    for (unsigned i = s + tid; i < t; i += 512)
        atomicAdd(&cnt[pairs[i] & 511u], 1u);
    __syncthreads();
    const unsigned v = cnt[tid];
    sc[tid] = v;
    __syncthreads();
    for (int o = 1; o < 512; o <<= 1) {
        unsigned q = tid >= o ? sc[tid - o] : 0u;
        __syncthreads();
        sc[tid] += q;
        __syncthreads();
    }
    const unsigned excl = sc[tid] - v;
    const int node = b * 512 + tid;
    if (node < nN) {
        dinv[node] = v > 0 ? rsqrtf((float)v) : 0.f;
        off[node] = (int)(s + excl);
    }
    if (b == 0 && tid == 0) off[nN] = nE;
    sc[tid] = excl;          // reuse as cursor
    __syncthreads();
    for (unsigned i = s + tid; i < t; i += 512) {
        unsigned p = pairs[i];
        unsigned pos = s + atomicAdd(&sc[p & 511u], 1u);
        srcs[pos] = (int)(p >> BSHIFT);
    }
}

// -------- 8x8-tiled GEMM: Yh[r] = half(dinv[r] * (X[r,128] @ W[128,DOUT])) --------
// Xs k-major [BK][BM+4]: a-reads are 2x ds_read_b128, broadcast within tx groups.
// Ws group-stride 12 (8 floats + 4 pad): b-read bank starts 12*tx mod 32 -> 2-way (free).
// Per thread per k: 64 B LDS for 64 FMAs = 1 B/FMA -> LDS/FMA pipes balanced.

template <int DOUT, int NT, int BM>
__launch_bounds__(NT)
__global__ void gemm_kernel(const float* __restrict__ X, const float* __restrict__ W,
                            const float* __restrict__ dinv, __half* __restrict__ Y, int nrows) {
    constexpr int BK = 32;
    constexpr int NTX = DOUT / 8;
    constexpr int NTY = NT / NTX;
    static_assert(NTY * 8 == BM, "thread map must cover BM rows");
    constexpr int XLDB = BM + 4;      // pad keeps 16B align (mult of 4) + spreads stage banks
    constexpr int WROW = NTX * 12;    // 8 payload + 4 pad per tx group
    __shared__ float Xs[BK * XLDB];
    __shared__ float Ws[BK * WROW];

    const int tid = threadIdx.x;
    const int tx = tid % NTX;
    const int ty = tid / NTX;
    const int r0 = blockIdx.x * BM;

    float acc[8][8];
#pragma unroll
    for (int i = 0; i < 8; ++i)
#pragma unroll
        for (int j = 0; j < 8; ++j) acc[i][j] = 0.f;

    for (int k0 = 0; k0 < 128; k0 += BK) {
        __syncthreads();
        // stage W chunk [BK][DOUT] -> padded groups
        for (int idx = tid; idx < BK * (DOUT / 4); idx += NT) {
            int r = idx / (DOUT / 4), c4 = idx % (DOUT / 4);
            float4 w = ((const float4*)W)[(size_t)(k0 + r) * (DOUT / 4) + c4];
            float* dst = &Ws[r * WROW + (c4 >> 1) * 12 + (c4 & 1) * 4];
            dst[0] = w.x; dst[1] = w.y; dst[2] = w.z; dst[3] = w.w;
        }
        // stage X chunk transposed: Xs[k][m]
        for (int idx = tid; idx < BM * (BK / 4); idx += NT) {
            int r = idx >> 3, q = idx & 7;         // BK/4 == 8
            int gr = min(r0 + r, nrows - 1);
            float4 x = ((const float4*)X)[(size_t)gr * 32 + (k0 >> 2) + q];
            Xs[(4 * q + 0) * XLDB + r] = x.x;
            Xs[(4 * q + 1) * XLDB + r] = x.y;
            Xs[(4 * q + 2) * XLDB + r] = x.z;
            Xs[(4 * q + 3) * XLDB + r] = x.w;
        }
        __syncthreads();

#pragma unroll 8
        for (int kk = 0; kk < BK; ++kk) {
            float4 a0 = *(const float4*)&Xs[kk * XLDB + ty * 8];
            float4 a1 = *(const float4*)&Xs[kk * XLDB + ty * 8 + 4];
            float4 w0 = *(const float4*)&Ws[kk * WROW + tx * 12];
            float4 w1 = *(const float4*)&Ws[kk * WROW + tx * 12 + 4];
            float a[8] = {a0.x, a0.y, a0.z, a0.w, a1.x, a1.y, a1.z, a1.w};
            float b[8] = {w0.x, w0.y, w0.z, w0.w, w1.x, w1.y, w1.z, w1.w};
#pragma unroll
            for (int i = 0; i < 8; ++i)
#pragma unroll
                for (int j = 0; j < 8; ++j)
                    acc[i][j] += a[i] * b[j];
        }
    }

#pragma unroll
    for (int i = 0; i < 8; ++i) {
        int r = r0 + ty * 8 + i;
        if (r < nrows) {
            float dv = dinv[r];
            union { __half h[8]; uint4 u; } o;
#pragma unroll
            for (int j = 0; j < 8; ++j) o.h[j] = __float2half(acc[i][j] * dv);
            *(uint4*)&Y[(size_t)r * DOUT + tx * 8] = o.u;
        }
    }
}

// -------- CSR gather (f16 rows): out[v] = relu(dinv[v] * sum_e XWh[srcs[e]] + b) --------
// One wave per destination node; 2-deep unrolled edge loop for MLP.

template <int D>
__launch_bounds__(256)
__global__ void gather_kernel(const __half* __restrict__ XW, const int* __restrict__ off,
                              const int* __restrict__ srcs, const float* __restrict__ dinv,
                              const float* __restrict__ bias, float* __restrict__ out, int nN) {
    constexpr int G   = D / 8;    // 16B chunks per row (16 for D=128, 8 for D=64)
    constexpr int EPW = 64 / G;   // edges in parallel per wave (4 or 8)
    const int lane = threadIdx.x & 63;
    const int g    = lane % G;
    const int sub  = lane / G;
    const int wid  = (blockIdx.x * blockDim.x + threadIdx.x) >> 6;
    const int nw   = (gridDim.x * blockDim.x) >> 6;

    for (int v = wid; v < nN; v += nw) {
        const int s1 = off[v + 1];
        int i = off[v] + sub;
        float acc[8];
#pragma unroll
        for (int k = 0; k < 8; ++k) acc[k] = 0.f;
        for (; i + EPW < s1; i += 2 * EPW) {
            int sa = srcs[i], sb = srcs[i + EPW];
            union { uint4 u; __half h[8]; } ca, cb;
            ca.u = ((const uint4*)(XW + (size_t)sa * D))[g];
            cb.u = ((const uint4*)(XW + (size_t)sb * D))[g];
#pragma unroll
            for (int k = 0; k < 8; ++k) acc[k] += __half2float(ca.h[k]);
#pragma unroll
            for (int k = 0; k < 8; ++k) acc[k] += __half2float(cb.h[k]);
        }
        if (i < s1) {
            union { uint4 u; __half h[8]; } cv;
            cv.u = ((const uint4*)(XW + (size_t)srcs[i] * D))[g];
#pragma unroll
            for (int k = 0; k < 8; ++k) acc[k] += __half2float(cv.h[k]);
        }
#pragma unroll
        for (int d = 32; d >= G; d >>= 1)
#pragma unroll
            for (int k = 0; k < 8; ++k) acc[k] += __shfl_down(acc[k], d);
        if (sub == 0) {
            float dv = dinv[v];
            float4 b0 = ((const float4*)bias)[g * 2];
            float4 b1 = ((const float4*)bias)[g * 2 + 1];
            float4 o0, o1;
            o0.x = fmaxf(dv * acc[0] + b0.x, 0.f);
            o0.y = fmaxf(dv * acc[1] + b0.y, 0.f);
            o0.z = fmaxf(dv * acc[2] + b0.z, 0.f);
            o0.w = fmaxf(dv * acc[3] + b0.w, 0.f);
            o1.x = fmaxf(dv * acc[4] + b1.x, 0.f);
            o1.y = fmaxf(dv * acc[5] + b1.y, 0.f);
            o1.z = fmaxf(dv * acc[6] + b1.z, 0.f);
            o1.w = fmaxf(dv * acc[7] + b1.w, 0.f);
            float4* op = (float4*)(out + (size_t)v * D + g * 8);
            op[0] = o0;
            op[1] = o1;
        }
    }
}

extern "C" void kernel_launch(void* const* d_in, const int* in_sizes, int n_in,
                              void* d_out, int out_size, void* d_ws, size_t ws_size,
                              hipStream_t stream) {
    const float* feats = (const float*)d_in[0];
    const int*   ei    = (const int*)d_in[1];
    const float* W1    = (const float*)d_in[2];
    const float* b1    = (const float*)d_in[3];
    const float* W2    = (const float*)d_in[4];
    const float* b2    = (const float*)d_in[5];
    const float* W3    = (const float*)d_in[6];
    const float* b3    = (const float*)d_in[7];

    const int N = in_sizes[0] / 128;
    const int E = in_sizes[1] / 2;
    const int* row = ei;       // source
    const int* col = ei + E;   // destination

    // workspace layout
    char* p = (char*)d_ws;
    unsigned* gHist = (unsigned*)p; p += ALIGNUP((size_t)256 * ABLK * 4);
    float*  dinv = (float*)p;       p += ALIGNUP((size_t)N * 4);
    int*    off  = (int*)p;         p += ALIGNUP((size_t)(N + 1) * 4);
    int*    srcs = (int*)p;         p += ALIGNUP((size_t)E * 4);
    __half* bufH = (__half*)p;      p += ALIGNUP((size_t)N * 128 * 2);
    float*  bufA = (float*)p;
    unsigned* pairs = (unsigned*)bufA;  // alias: pairs consumed before gather1 writes bufA

    // ---- CSR build (no global atomics) ----
    const int chunk = (E + ABLK - 1) / ABLK;
    const int NB    = (N + 511) >> BSHIFT;
    bucket_hist_kernel<<<ABLK, 256, 0, stream>>>(col, gHist, E, chunk);
    bucket_scan_kernel<<<1, 1024, 0, stream>>>(gHist);
    bucket_scatter_kernel<<<ABLK, 256, 0, stream>>>(row, col, gHist, pairs, E, chunk);
    bucket_sort_kernel<<<NB, 512, 0, stream>>>(pairs, gHist, srcs, off, dinv, N, E);

    const int GB = (N + 3) / 4;       // gather: 4 waves/block

    // ---- layer 1: feats @ W1 -> bufH (f16); agg -> bufA (f32) ----
    gemm_kernel<128, 256, 128><<<(N + 127) / 128, 256, 0, stream>>>(feats, W1, dinv, bufH, N);
    gather_kernel<128><<<GB, 256, 0, stream>>>(bufH, off, srcs, dinv, b1, bufA, N);
    // ---- layer 2: bufA @ W2 -> bufH; agg -> bufA (gather reads only bufH) ----
    gemm_kernel<128, 256, 128><<<(N + 127) / 128, 256, 0, stream>>>(bufA, W2, dinv, bufH, N);
    gather_kernel<128><<<GB, 256, 0, stream>>>(bufH, off, srcs, dinv, b2, bufA, N);
    // ---- layer 3: bufA @ W3 -> bufH (64-wide); agg -> d_out ----
    gemm_kernel<64, 256, 256><<<(N + 255) / 256, 256, 0, stream>>>(bufA, W3, dinv, bufH, N);
    gather_kernel<64><<<GB, 256, 0, stream>>>(bufH, off, srcs, dinv, b3, (float*)d_out, N);
}

// Round 7
// 299.768 us; speedup vs baseline: 1.3251x; 1.3251x over previous
//
#include <hip/hip_runtime.h>

#define ALIGNUP(x) (((x) + 255) & ~(size_t)255)
#define ABLK 256          // blocks for hist/scatter passes
#define BSHIFT 9          // 512 dst nodes per bucket; requires N <= 131072

typedef _Float16 f16x8 __attribute__((ext_vector_type(8)));
typedef float f32x4 __attribute__((ext_vector_type(4)));

// ---------------- CSR build: two-level counting sort, LDS atomics only ----------------

__global__ void bucket_hist_kernel(const int* __restrict__ col, unsigned* __restrict__ gHist,
                                   int nE, int chunk) {
    __shared__ unsigned hist[256];
    const int tid = threadIdx.x, blk = blockIdx.x;
    hist[tid] = 0;
    __syncthreads();
    const int e0 = blk * chunk, e1 = min(nE, e0 + chunk);
    for (int e = e0 + tid; e < e1; e += 256)
        atomicAdd(&hist[((unsigned)col[e]) >> BSHIFT], 1u);
    __syncthreads();
    gHist[tid * ABLK + blk] = hist[tid];   // bucket-major
}

__global__ void bucket_scan_kernel(unsigned* __restrict__ g) {
    __shared__ unsigned ps[1024];
    const int tid = threadIdx.x;
    const int base = tid * 64;
    unsigned sum = 0;
    for (int k = 0; k < 64; ++k) sum += g[base + k];
    ps[tid] = sum;
    __syncthreads();
    for (int o = 1; o < 1024; o <<= 1) {
        unsigned t = tid >= o ? ps[tid - o] : 0u;
        __syncthreads();
        ps[tid] += t;
        __syncthreads();
    }
    unsigned run = ps[tid] - sum;
    for (int k = 0; k < 64; ++k) {
        unsigned v = g[base + k];
        g[base + k] = run;
        run += v;
    }
}

__global__ void bucket_scatter_kernel(const int* __restrict__ row, const int* __restrict__ col,
                                      const unsigned* __restrict__ gScan,
                                      unsigned* __restrict__ pairs, int nE, int chunk) {
    __shared__ unsigned basec[256];
    const int tid = threadIdx.x, blk = blockIdx.x;
    basec[tid] = gScan[tid * ABLK + blk];
    __syncthreads();
    const int e0 = blk * chunk, e1 = min(nE, e0 + chunk);
    for (int e = e0 + tid; e < e1; e += 256) {
        unsigned d = (unsigned)col[e];
        unsigned pos = atomicAdd(&basec[d >> BSHIFT], 1u);
        pairs[pos] = (((unsigned)row[e]) << BSHIFT) | (d & 511u);  // src(17b) | dstLow(9b)
    }
}

__global__ void bucket_sort_kernel(const unsigned* __restrict__ pairs,
                                   const unsigned* __restrict__ gScan,
                                   int* __restrict__ srcs, int* __restrict__ off,
                                   float* __restrict__ dinv, int nN, int nE) {
    __shared__ unsigned cnt[512], sc[512];
    const int tid = threadIdx.x, b = blockIdx.x;
    const unsigned s = gScan[b * ABLK];
    const unsigned t = (b + 1 < 256) ? gScan[(b + 1) * ABLK] : (unsigned)nE;
    cnt[tid] = 0;
    __syncthreads();
    for (unsigned i = s + tid; i < t; i += 512)
        atomicAdd(&cnt[pairs[i] & 511u], 1u);
    __syncthreads();
    const unsigned v = cnt[tid];
    sc[tid] = v;
    __syncthreads();
    for (int o = 1; o < 512; o <<= 1) {
        unsigned q = tid >= o ? sc[tid - o] : 0u;
        __syncthreads();
        sc[tid] += q;
        __syncthreads();
    }
    const unsigned excl = sc[tid] - v;
    const int node = b * 512 + tid;
    if (node < nN) {
        dinv[node] = v > 0 ? rsqrtf((float)v) : 0.f;
        off[node] = (int)(s + excl);
    }
    if (b == 0 && tid == 0) off[nN] = nE;
    sc[tid] = excl;          // reuse as cursor
    __syncthreads();
    for (unsigned i = s + tid; i < t; i += 512) {
        unsigned p = pairs[i];
        unsigned pos = s + atomicAdd(&sc[p & 511u], 1u);
        srcs[pos] = (int)(p >> BSHIFT);
    }
}

// -------- MFMA GEMM: Yh[r] = f16(dinv[r] * (X[r,128] @ W[128,DOUT])) --------
// v_mfma_f32_16x16x32_f16. Per block: 4 waves x 16 rows = 64-row chunks, full DOUT width.
// W staged in LDS pre-swizzled to FRAGMENT ORDER: Wf[(j*4+k)*64 + lane] is the 16B b-frag
// chunk for n-tile j, k-step k -> every ds_read is lane l -> chunk l of a contiguous 1KB
// region: canonical conflict-free pattern (no padding arithmetic to get wrong).
// A frags load straight from global: row = l&15, k = kstep*32 + (l>>4)*8 + [0..7]
// (16 rows x 64B contiguous per instruction). C/D: col = lane&15, row = (lane>>4)*4 + reg.

template <int DOUT, bool AF32>
__launch_bounds__(256)
__global__ void gemm_mfma(const void* __restrict__ Xv, const float* __restrict__ W,
                          const float* __restrict__ dinv, _Float16* __restrict__ Y, int nrows) {
    constexpr int NTILE = DOUT / 16;
    __shared__ f16x8 Wf[NTILE * 4 * 64];
    const int tid = threadIdx.x;
    // stage W (f32 [k][DOUT]) -> fragment-order f16
    for (int idx = tid; idx < 128 * (DOUT / 4); idx += 256) {
        const int kk = idx / (DOUT / 4);
        const int n4 = (idx % (DOUT / 4)) * 4;
        const float4 w = ((const float4*)W)[idx];
        const int fk = kk >> 5, kb = (kk >> 3) & 3, e = kk & 7;
        const float wv[4] = {w.x, w.y, w.z, w.w};
#pragma unroll
        for (int d = 0; d < 4; ++d) {
            const int n = n4 + d;
            const int j = n >> 4;
            const int l = (n & 15) | (kb << 4);
            ((_Float16*)&Wf[(j * 4 + fk) * 64 + l])[e] = (_Float16)wv[d];
        }
    }
    __syncthreads();

    const int lane = tid & 63;
    const int wvid = tid >> 6;
    const int m = lane & 15;
    const int kb = lane >> 4;
    const int nchunks = (nrows + 63) >> 6;

    for (int c = blockIdx.x; c < nchunks; c += gridDim.x) {
        const int r0 = c * 64 + wvid * 16;
        const int arow = min(r0 + m, nrows - 1);
        f16x8 a[4];
        if constexpr (AF32) {
            const float* Xp = (const float*)Xv + (size_t)arow * 128 + kb * 8;
#pragma unroll
            for (int k = 0; k < 4; ++k) {
                const float4 x0 = *(const float4*)(Xp + k * 32);
                const float4 x1 = *(const float4*)(Xp + k * 32 + 4);
                f16x8 t;
                t[0] = (_Float16)x0.x; t[1] = (_Float16)x0.y;
                t[2] = (_Float16)x0.z; t[3] = (_Float16)x0.w;
                t[4] = (_Float16)x1.x; t[5] = (_Float16)x1.y;
                t[6] = (_Float16)x1.z; t[7] = (_Float16)x1.w;
                a[k] = t;
            }
        } else {
            const _Float16* Xp = (const _Float16*)Xv + (size_t)arow * 128 + kb * 8;
#pragma unroll
            for (int k = 0; k < 4; ++k) a[k] = *(const f16x8*)(Xp + k * 32);
        }
        f32x4 acc[NTILE];
#pragma unroll
        for (int j = 0; j < NTILE; ++j) acc[j] = (f32x4){0.f, 0.f, 0.f, 0.f};
#pragma unroll
        for (int k = 0; k < 4; ++k)
#pragma unroll
            for (int j = 0; j < NTILE; ++j)   // j-inner: 8 independent acc chains
                acc[j] = __builtin_amdgcn_mfma_f32_16x16x32_f16(
                             a[k], Wf[(j * 4 + k) * 64 + lane], acc[j], 0, 0, 0);
#pragma unroll
        for (int i = 0; i < 4; ++i) {
            const int r = r0 + kb * 4 + i;
            if (r < nrows) {
                const float dv = dinv[r];
#pragma unroll
                for (int j = 0; j < NTILE; ++j)
                    Y[(size_t)r * DOUT + j * 16 + m] = (_Float16)(acc[j][i] * dv);
            }
        }
    }
}

// -------- CSR gather (f16 rows): out[v] = relu(dinv[v] * sum_e XWh[srcs[e]] + b) --------
// One wave per destination node; 2-deep unrolled edge loop for MLP.
// OT = _Float16 (feeds next MFMA gemm) or float (final output).

template <int D, typename OT>
__launch_bounds__(256)
__global__ void gather_kernel(const _Float16* __restrict__ XW, const int* __restrict__ off,
                              const int* __restrict__ srcs, const float* __restrict__ dinv,
                              const float* __restrict__ bias, OT* __restrict__ out, int nN) {
    constexpr int G   = D / 8;    // 16B chunks per row (16 for D=128, 8 for D=64)
    constexpr int EPW = 64 / G;   // edges in parallel per wave (4 or 8)
    const int lane = threadIdx.x & 63;
    const int g    = lane % G;
    const int sub  = lane / G;
    const int wid  = (blockIdx.x * blockDim.x + threadIdx.x) >> 6;
    const int nw   = (gridDim.x * blockDim.x) >> 6;

    for (int v = wid; v < nN; v += nw) {
        const int s1 = off[v + 1];
        int i = off[v] + sub;
        float acc[8];
#pragma unroll
        for (int k = 0; k < 8; ++k) acc[k] = 0.f;
        for (; i + EPW < s1; i += 2 * EPW) {
            int sa = srcs[i], sb = srcs[i + EPW];
            union { uint4 u; _Float16 h[8]; } ca, cb;
            ca.u = ((const uint4*)(XW + (size_t)sa * D))[g];
            cb.u = ((const uint4*)(XW + (size_t)sb * D))[g];
#pragma unroll
            for (int k = 0; k < 8; ++k) acc[k] += (float)ca.h[k];
#pragma unroll
            for (int k = 0; k < 8; ++k) acc[k] += (float)cb.h[k];
        }
        if (i < s1) {
            union { uint4 u; _Float16 h[8]; } cv;
            cv.u = ((const uint4*)(XW + (size_t)srcs[i] * D))[g];
#pragma unroll
            for (int k = 0; k < 8; ++k) acc[k] += (float)cv.h[k];
        }
#pragma unroll
        for (int d = 32; d >= G; d >>= 1)
#pragma unroll
            for (int k = 0; k < 8; ++k) acc[k] += __shfl_down(acc[k], d);
        if (sub == 0) {
            const float dv = dinv[v];
            const float4 b0 = ((const float4*)bias)[g * 2];
            const float4 b1 = ((const float4*)bias)[g * 2 + 1];
            float o[8];
            o[0] = fmaxf(dv * acc[0] + b0.x, 0.f);
            o[1] = fmaxf(dv * acc[1] + b0.y, 0.f);
            o[2] = fmaxf(dv * acc[2] + b0.z, 0.f);
            o[3] = fmaxf(dv * acc[3] + b0.w, 0.f);
            o[4] = fmaxf(dv * acc[4] + b1.x, 0.f);
            o[5] = fmaxf(dv * acc[5] + b1.y, 0.f);
            o[6] = fmaxf(dv * acc[6] + b1.z, 0.f);
            o[7] = fmaxf(dv * acc[7] + b1.w, 0.f);
            if constexpr (sizeof(OT) == 2) {
                union { uint4 u; _Float16 h[8]; } ov;
#pragma unroll
                for (int k = 0; k < 8; ++k) ov.h[k] = (_Float16)o[k];
                *(uint4*)((_Float16*)out + (size_t)v * D + g * 8) = ov.u;
            } else {
                float4 o0 = make_float4(o[0], o[1], o[2], o[3]);
                float4 o1 = make_float4(o[4], o[5], o[6], o[7]);
                float4* op = (float4*)((float*)out + (size_t)v * D + g * 8);
                op[0] = o0;
                op[1] = o1;
            }
        }
    }
}

extern "C" void kernel_launch(void* const* d_in, const int* in_sizes, int n_in,
                              void* d_out, int out_size, void* d_ws, size_t ws_size,
                              hipStream_t stream) {
    const float* feats = (const float*)d_in[0];
    const int*   ei    = (const int*)d_in[1];
    const float* W1    = (const float*)d_in[2];
    const float* b1    = (const float*)d_in[3];
    const float* W2    = (const float*)d_in[4];
    const float* b2    = (const float*)d_in[5];
    const float* W3    = (const float*)d_in[6];
    const float* b3    = (const float*)d_in[7];

    const int N = in_sizes[0] / 128;
    const int E = in_sizes[1] / 2;
    const int* row = ei;       // source
    const int* col = ei + E;   // destination

    // workspace layout
    char* p = (char*)d_ws;
    unsigned* gHist = (unsigned*)p; p += ALIGNUP((size_t)256 * ABLK * 4);
    float*     dinv = (float*)p;    p += ALIGNUP((size_t)N * 4);
    int*       off  = (int*)p;      p += ALIGNUP((size_t)(N + 1) * 4);
    int*       srcs = (int*)p;      p += ALIGNUP((size_t)E * 4);
    _Float16*  bufW = (_Float16*)p; p += ALIGNUP((size_t)N * 128 * 2);   // XW (gemm out)
    _Float16*  bufX = (_Float16*)p;                                       // h (gather out)
    unsigned* pairs = (unsigned*)bufX;  // alias: pairs consumed before gather1 writes bufX

    // ---- CSR build (no global atomics) ----
    const int chunk = (E + ABLK - 1) / ABLK;
    const int NB    = (N + 511) >> BSHIFT;
    bucket_hist_kernel<<<ABLK, 256, 0, stream>>>(col, gHist, E, chunk);
    bucket_scan_kernel<<<1, 1024, 0, stream>>>(gHist);
    bucket_scatter_kernel<<<ABLK, 256, 0, stream>>>(row, col, gHist, pairs, E, chunk);
    bucket_sort_kernel<<<NB, 512, 0, stream>>>(pairs, gHist, srcs, off, dinv, N, E);

    const int NCH = (N + 63) / 64;        // 64-row gemm chunks
    const int GG  = NCH < 800 ? NCH : 800;
    const int GB  = (N + 3) / 4;          // gather: 4 waves/block

    // ---- layer 1: feats(f32) @ W1 -> bufW (f16); agg -> bufX (f16) ----
    gemm_mfma<128, true><<<GG, 256, 0, stream>>>(feats, W1, dinv, bufW, N);
    gather_kernel<128, _Float16><<<GB, 256, 0, stream>>>(bufW, off, srcs, dinv, b1, bufX, N);
    // ---- layer 2 ----
    gemm_mfma<128, false><<<GG, 256, 0, stream>>>(bufX, W2, dinv, bufW, N);
    gather_kernel<128, _Float16><<<GB, 256, 0, stream>>>(bufW, off, srcs, dinv, b2, bufX, N);
    // ---- layer 3: DOUT=64; agg -> d_out (f32) ----
    gemm_mfma<64, false><<<GG, 256, 0, stream>>>(bufX, W3, dinv, bufW, N);
    gather_kernel<64, float><<<GB, 256, 0, stream>>>(bufW, off, srcs, dinv, b3,
                                                     (float*)d_out, N);
}